// Round 16
// baseline (139.022 us; speedup 1.0000x reference)
//
#include <hip/hip_runtime.h>
#include <hip/hip_bf16.h>
#include <math.h>

typedef __attribute__((ext_vector_type(8))) short bf16x8;
typedef __attribute__((ext_vector_type(4))) float f32x4;

__device__ inline unsigned short f2bf(float x) {
  __hip_bfloat16 h = __float2bfloat16(x);
  return __builtin_bit_cast(unsigned short, h);
}
__device__ inline float bf2f(unsigned short u) {
  unsigned v = ((unsigned)u) << 16;
  return __builtin_bit_cast(float, v);
}
// One-instruction RNE pack of two f32 -> packed bf16x2 (low = a, high = b).
__device__ inline unsigned cvtpk(float a, float b) {
  unsigned r;
  asm("v_cvt_pk_bf16_f32 %0, %1, %2" : "=v"(r) : "v"(a), "v"(b));
  return r;
}

// ===========================================================================
// D1: weight split (88 blocks) + 4x4 avg pool (576 blocks), fused dispatch.
// ===========================================================================
__global__ __launch_bounds__(256)
void prep_kernel(const float* __restrict__ w0, const float* __restrict__ w1,
                 const float* __restrict__ w2, const float* __restrict__ w3,
                 const float* __restrict__ w4, const float* __restrict__ w5,
                 unsigned short* __restrict__ d0, unsigned short* __restrict__ d1,
                 unsigned short* __restrict__ d2, unsigned short* __restrict__ d3,
                 unsigned short* __restrict__ d4, unsigned short* __restrict__ d5,
                 const float* __restrict__ x, float* __restrict__ xg) {
  int idx = blockIdx.x * 256 + threadIdx.x;
  if (idx < 22528) {
    int r = idx;
    const float* src; unsigned short* dst;
    if (r < 6144) { src = w0; dst = d0; }
    else if (r < 8192) { src = w1; dst = d1; r -= 6144; }
    else if (r < 14336) { src = w2; dst = d2; r -= 8192; }
    else if (r < 16384) { src = w3; dst = d3; r -= 14336; }
    else if (r < 20480) { src = w4; dst = d4; r -= 16384; }
    else { src = w5; dst = d5; r -= 20480; }
    const float* in = src + (size_t)r * 32;
    union { unsigned short u[32]; uint4 q[4]; } H, L;
#pragma unroll
    for (int i = 0; i < 32; ++i) {
      float v = in[i];
      unsigned short h = f2bf(v);
      H.u[i] = h;
      L.u[i] = f2bf(v - bf2f(h));
    }
    uint4* op = (uint4*)(dst + (size_t)r * 64);
#pragma unroll
    for (int q = 0; q < 4; ++q) { op[q] = H.q[q]; op[4 + q] = L.q[q]; }
  } else {
    int p = idx - 22528;
    if (p >= 4 * 256 * 144) return;
    int wc = p % 12;
    int t = p / 12;
    int hc = t % 12;
    int bc = t / 12;
    const float* src = x + ((size_t)bc * 48 + hc * 4) * 48 + wc * 4;
    float s = 0.f;
#pragma unroll
    for (int dy = 0; dy < 4; ++dy)
#pragma unroll
      for (int dx = 0; dx < 4; ++dx) s += src[dy * 48 + dx];
    xg[p] = s * (1.0f / 16.0f);
  }
}

// ===========================================================================
// conv1x1 body: Y = (Whi [+ Wlo]) . Xhi  (+bias, +act). TERMS = 1 or 2.
// Full-tile LDS staging: Bs[64 s][256 k] bf16 (32 KB), staged in 8-kb
// super-steps -> 2 barriers per 256-k (vs 16), MFMA loop barrier-free.
// Slot swizzle: 16B-slot ^= (row & 7)  (bank-balanced writes AND reads).
// CKS>0 : X = bf16 opart partials + f32 lpart denominators (fused combine).
// UPS   : Cin=512; kb<8 reads bf16 X, kb>=8 bilinear-upsamples f32 gsm inline.
// EPI=1 : qkv epilogue — L2-normalize q/k per head and write bf16 q
//         (pre-scaled), permuted k, d-major v directly.
// ===========================================================================
template<int ACT, int OT, int CKS, int UPS, int EPI, int TERMS, typename XT, typename YT>
__device__ __forceinline__
void conv_body(const unsigned short* __restrict__ Whl, const XT* __restrict__ X,
               const float* __restrict__ lpart, const float* __restrict__ bias,
               YT* __restrict__ Y, const float* __restrict__ gsm,
               unsigned short* __restrict__ qd, unsigned short* __restrict__ kd,
               unsigned short* __restrict__ vt, int Sp,
               int Cin, int S, size_t XbS, size_t YbS,
               int bx, int by, int bz, int tid) {
  constexpr int OI = OT / 64;
  __shared__ __align__(16) unsigned short Bs[64 * 256];  // 32 KB
  const int w = tid >> 6, lane = tid & 63;
  const int g = lane >> 4, c = lane & 15;
  const int s0 = bx * 64;
  const int o0 = by * OT;
  const int b = bz;
  const int KB = Cin >> 5;
  const int sRow = tid & 63;
  const int jS = tid >> 6;
  const int ss = s0 + sRow;
  const bool sIn = (ss < S);
  const int swz = sRow & 7;

  int t00 = 0, t01 = 0, t10 = 0, t11 = 0;
  float w00 = 0.f, w01 = 0.f, w10 = 0.f, w11 = 0.f;
  if constexpr (UPS) {
    if (sIn) {
      int yo = ss / 48, xo = ss % 48;
      float sy = 0.25f * yo - 0.375f;
      float sx = 0.25f * xo - 0.375f;
      int y0 = (int)floorf(sy); float fy = sy - (float)y0;
      int x0 = (int)floorf(sx); float fx = sx - (float)x0;
      int y0c = min(11, max(0, y0)), y1c = min(11, max(0, y0 + 1));
      int x0c = min(11, max(0, x0)), x1c = min(11, max(0, x0 + 1));
      t00 = y0c * 12 + x0c; t01 = y0c * 12 + x1c;
      t10 = y1c * 12 + x0c; t11 = y1c * 12 + x1c;
      w00 = (1.f - fy) * (1.f - fx); w01 = (1.f - fy) * fx;
      w10 = fy * (1.f - fx);         w11 = fy * fx;
    }
  }

  f32x4 acc[OI][4];
#pragma unroll
  for (int oi = 0; oi < OI; ++oi)
#pragma unroll
    for (int si = 0; si < 4; ++si) acc[oi][si] = (f32x4){0.f, 0.f, 0.f, 0.f};

  for (int kbb = 0; kbb < KB; kbb += 8) {
    __syncthreads();  // previous super-step fully consumed
#pragma unroll
    for (int kb2 = 0; kb2 < 8; ++kb2) {
      int kb = kbb + kb2;
      union { unsigned u[4]; bf16x8 v; } hu;
      if (sIn) {
        if constexpr (CKS > 0) {
          // fused attention-combine: head index == kb; opart is bf16.
          const unsigned short* xp = (const unsigned short*)X + (size_t)b * XbS +
                                     (size_t)(kb * 32 + 8 * jS) * S + ss;
          const float* lp = lpart + ((size_t)b * 8 + kb) * S + ss;
          float den = 0.f;
          float num[8] = {0.f, 0.f, 0.f, 0.f, 0.f, 0.f, 0.f, 0.f};
#pragma unroll
          for (int ksi = 0; ksi < CKS; ++ksi) {
            den += lp[(size_t)ksi * 32 * S];
#pragma unroll
            for (int i = 0; i < 8; ++i)
              num[i] += bf2f(xp[(size_t)(ksi * 1024 + i) * S]);
          }
          float rd = 1.0f / den;
#pragma unroll
          for (int i = 0; i < 4; ++i)
            hu.u[i] = cvtpk(num[2 * i] * rd, num[2 * i + 1] * rd);
        } else if constexpr (UPS) {
          if (kb < 8) {
            const XT* xp = X + (size_t)b * XbS + (size_t)(kb * 32 + 8 * jS) * S + ss;
#pragma unroll
            for (int i = 0; i < 4; ++i) {
              unsigned lo = *(const unsigned short*)(xp + (size_t)(2 * i) * S);
              unsigned hi = *(const unsigned short*)(xp + (size_t)(2 * i + 1) * S);
              hu.u[i] = lo | (hi << 16);
            }
          } else {
            const float* gbb = gsm + (size_t)b * 256 * 144 +
                               (size_t)((kb - 8) * 32 + 8 * jS) * 144;
#pragma unroll
            for (int i = 0; i < 4; ++i) {
              const float* g0 = gbb + (size_t)(2 * i) * 144;
              const float* g1 = gbb + (size_t)(2 * i + 1) * 144;
              float v0 = w00 * g0[t00] + w01 * g0[t01] + w10 * g0[t10] + w11 * g0[t11];
              float v1 = w00 * g1[t00] + w01 * g1[t01] + w10 * g1[t10] + w11 * g1[t11];
              hu.u[i] = cvtpk(v0, v1);
            }
          }
        } else if constexpr (sizeof(XT) == 2) {
          const XT* xp = X + (size_t)b * XbS + (size_t)(kb * 32 + 8 * jS) * S + ss;
#pragma unroll
          for (int i = 0; i < 4; ++i) {
            unsigned lo = *(const unsigned short*)(xp + (size_t)(2 * i) * S);
            unsigned hi = *(const unsigned short*)(xp + (size_t)(2 * i + 1) * S);
            hu.u[i] = lo | (hi << 16);
          }
        } else {
          const float* xp = (const float*)X + (size_t)b * XbS +
                            (size_t)(kb * 32 + 8 * jS) * S + ss;
#pragma unroll
          for (int i = 0; i < 4; ++i)
            hu.u[i] = cvtpk(xp[(size_t)(2 * i) * S], xp[(size_t)(2 * i + 1) * S]);
        }
      } else {
#pragma unroll
        for (int i = 0; i < 4; ++i) hu.u[i] = 0;
      }
      *(bf16x8*)(Bs + sRow * 256 + (((kb2 << 2) + jS) ^ swz) * 8) = hu.v;
    }
    __syncthreads();
    // ---- barrier-free MFMA over the staged 8 kb ----
#pragma unroll
    for (int kb2 = 0; kb2 < 8; ++kb2) {
      int kb = kbb + kb2;
      bf16x8 ahi[OI], alo[OI];
#pragma unroll
      for (int oi = 0; oi < OI; ++oi) {
        const unsigned short* ap =
            Whl + ((size_t)(o0 + 16 * OI * w + 16 * oi + c) * KB + kb) * 64;
        ahi[oi] = *(const bf16x8*)(ap + 8 * g);
        if constexpr (TERMS == 2) alo[oi] = *(const bf16x8*)(ap + 32 + 8 * g);
      }
      bf16x8 bhi[4];
#pragma unroll
      for (int si = 0; si < 4; ++si) {
        int row = 16 * si + c;
        bhi[si] = *(const bf16x8*)(Bs + row * 256 + ((((kb2 << 2) + g) ^ (row & 7)) * 8));
      }
#pragma unroll
      for (int oi = 0; oi < OI; ++oi)
#pragma unroll
        for (int si = 0; si < 4; ++si) {
          acc[oi][si] = __builtin_amdgcn_mfma_f32_16x16x32_bf16(ahi[oi], bhi[si], acc[oi][si], 0, 0, 0);
          if constexpr (TERMS == 2)
            acc[oi][si] = __builtin_amdgcn_mfma_f32_16x16x32_bf16(alo[oi], bhi[si], acc[oi][si], 0, 0, 0);
        }
    }
  }

  if constexpr (EPI == 1) {
    // qkv fused epilogue. o = o0 + 32w + 16oi + 4g + r; sec: 0=q 1=k 2=v.
    int sec = o0 >> 8;
    int h = ((o0 >> 5) & 7) + w;
    if (sec == 2) {
      unsigned short* vb = vt + (size_t)(b * 8 + h) * 32 * Sp;
#pragma unroll
      for (int oi = 0; oi < OI; ++oi)
#pragma unroll
        for (int r = 0; r < 4; ++r) {
          int d = 16 * oi + 4 * g + r;
#pragma unroll
          for (int si = 0; si < 4; ++si) {
            int s = s0 + 16 * si + c;
            if (s < S) vb[(size_t)d * Sp + s] = f2bf(acc[oi][si][r]);
          }
        }
    } else {
      float invs[4];
#pragma unroll
      for (int si = 0; si < 4; ++si) {
        float t = 0.f;
#pragma unroll
        for (int oi = 0; oi < OI; ++oi)
#pragma unroll
          for (int r = 0; r < 4; ++r) t += acc[oi][si][r] * acc[oi][si][r];
        t += __shfl_xor(t, 16, 64);
        t += __shfl_xor(t, 32, 64);
        float inv = 1.0f / fmaxf(sqrtf(t), 1e-12f);
        if (sec == 0) inv *= 0.25506607138105343f;  // 32^-0.5 * log2(e)
        invs[si] = inv;
      }
      unsigned short* dstp = (sec == 0) ? qd : kd;
#pragma unroll
      for (int si = 0; si < 4; ++si) {
        int s = s0 + 16 * si + c;
        if (s >= S) continue;
        int srow = s;
        if (sec == 1) {
          int blk2 = s >> 6, j = s & 63;
          srow = (blk2 << 6) + 32 * ((j >> 2) & 1) + 16 * (j >> 5) + 4 * ((j >> 3) & 3) + (j & 3);
        }
        unsigned short* rowp = dstp + ((size_t)(b * 8 + h) * Sp + srow) * 32;
#pragma unroll
        for (int oi = 0; oi < OI; ++oi) {
          int d0 = 16 * oi + 4 * g;
          *(unsigned*)(rowp + d0)     = cvtpk(acc[oi][si][0] * invs[si], acc[oi][si][1] * invs[si]);
          *(unsigned*)(rowp + d0 + 2) = cvtpk(acc[oi][si][2] * invs[si], acc[oi][si][3] * invs[si]);
        }
      }
    }
    return;
  }

#pragma unroll
  for (int oi = 0; oi < OI; ++oi) {
#pragma unroll
    for (int r = 0; r < 4; ++r) {
      int o = o0 + 16 * OI * w + 16 * oi + 4 * g + r;
      float bv = bias ? bias[o] : 0.f;
#pragma unroll
      for (int si = 0; si < 4; ++si) {
        int s = s0 + 16 * si + c;
        if (s < S) {
          float v = acc[oi][si][r] + bv;
          if (ACT == 1) v = v * 0.5f * (1.0f + erff(v * 0.70710678118654752f));
          if constexpr (sizeof(YT) == 2)
            Y[(size_t)b * YbS + (size_t)o * S + s] = (YT)f2bf(v);
          else
            Y[(size_t)b * YbS + (size_t)o * S + s] = v;
        }
      }
    }
  }
}

// D2: qkv convs (1-term) with fused l2norm/convert epilogue.
__global__ __launch_bounds__(256)
void qkv_conv_kernel(const unsigned short* __restrict__ Wl, const float* __restrict__ Xl,
                     unsigned short* __restrict__ qr_l, unsigned short* __restrict__ kr_l,
                     unsigned short* __restrict__ vt_l,
                     const unsigned short* __restrict__ Wg, const float* __restrict__ Xg,
                     unsigned short* __restrict__ qr_g, unsigned short* __restrict__ kr_g,
                     unsigned short* __restrict__ vt_g) {
  if (blockIdx.y < 6) {
    conv_body<0, 128, 0, 0, 1, 1, float, float>(Wl, Xl, nullptr, nullptr, (float*)nullptr, nullptr,
        qr_l, kr_l, vt_l, 2304,
        256, 2304, (size_t)256 * 2304, 0,
        blockIdx.x, blockIdx.y, blockIdx.z, threadIdx.x);
  } else {
    if (blockIdx.x >= 3) return;
    conv_body<0, 128, 0, 0, 1, 1, float, float>(Wg, Xg, nullptr, nullptr, (float*)nullptr, nullptr,
        qr_g, kr_g, vt_g, 256,
        256, 144, (size_t)256 * 144, 0,
        blockIdx.x, blockIdx.y - 6, blockIdx.z, threadIdx.x);
  }
}

// D4: proj convs with fused attention-combine (bf16 opart).
__global__ __launch_bounds__(256)
void proj_conv_kernel(const unsigned short* __restrict__ Wl, const unsigned short* __restrict__ opl,
                      const float* __restrict__ lpl, const float* __restrict__ bl,
                      unsigned short* __restrict__ cat,
                      const unsigned short* __restrict__ Wg, const unsigned short* __restrict__ opg,
                      const float* __restrict__ lpg, const float* __restrict__ bg,
                      float* __restrict__ gsm) {
  if (blockIdx.y < 4) {
    conv_body<0, 64, 3, 0, 0, 2, unsigned short, unsigned short>(Wl, opl, lpl, bl, cat, nullptr,
        nullptr, nullptr, nullptr, 0,
        256, 2304, (size_t)256 * 2304, (size_t)256 * 2304,
        blockIdx.x, blockIdx.y, blockIdx.z, threadIdx.x);
  } else {
    if (blockIdx.x >= 3) return;
    conv_body<0, 64, 3, 0, 0, 2, unsigned short, float>(Wg, opg, lpg, bg, gsm, nullptr,
        nullptr, nullptr, nullptr, 0,
        256, 144, (size_t)256 * 144, (size_t)256 * 144,
        blockIdx.x, blockIdx.y - 4, blockIdx.z, threadIdx.x);
  }
}

// D5: f1 conv (GELU) with inline bilinear upsample for channels 256..511.
__global__ __launch_bounds__(256)
void f1_conv_kernel(const unsigned short* __restrict__ W, const unsigned short* __restrict__ cat,
                    const float* __restrict__ gsm, const float* __restrict__ bias,
                    unsigned short* __restrict__ hbuf) {
  conv_body<1, 64, 0, 1, 0, 2, unsigned short, unsigned short>(W, cat, nullptr, bias, hbuf, gsm,
      nullptr, nullptr, nullptr, 0,
      512, 2304, (size_t)256 * 2304, (size_t)256 * 2304,
      blockIdx.x, blockIdx.y, blockIdx.z, threadIdx.x);
}

// D6: f2 conv, bf16 in -> f32 out.
__global__ __launch_bounds__(256)
void f2_conv_kernel(const unsigned short* __restrict__ W, const unsigned short* __restrict__ hbuf,
                    const float* __restrict__ bias, float* __restrict__ out) {
  conv_body<0, 64, 0, 0, 0, 2, unsigned short, float>(W, hbuf, nullptr, bias, out, nullptr,
      nullptr, nullptr, nullptr, 0,
      256, 2304, (size_t)256 * 2304, (size_t)256 * 2304,
      blockIdx.x, blockIdx.y, blockIdx.z, threadIdx.x);
}

// ===========================================================================
// D3: MFMA flash attention (unchanged round-15 body; bf16 opart).
// 64 q-rows/wave, K-split KS=3, phase-paired softmax, K prefetch 1 ahead.
// GRID (8=h, 27 local + 3 global, b): lin%8==h pins heads to XCDs.
// ===========================================================================
template<int KS>
__device__ __forceinline__
void attn_body(const unsigned short* __restrict__ qr, const unsigned short* __restrict__ kr,
               const unsigned short* __restrict__ vt, unsigned short* __restrict__ opart,
               float* __restrict__ lpart, int S, int Sp, int qblk, int ks,
               int h, int b, int tidx) {
  int w = tidx >> 6, lane = tidx & 63;
  int g = lane >> 4, c = lane & 15;
  int q0 = qblk * 256 + w * 64;
  const int chunks = Sp >> 6;
  const int c0 = (ks * chunks) / KS, c1 = ((ks + 1) * chunks) / KS;
  const unsigned short* qbh = qr + (size_t)(b * 8 + h) * Sp * 32;
  const unsigned short* kbh = kr + (size_t)(b * 8 + h) * Sp * 32;
  const unsigned short* vbh = vt + (size_t)(b * 8 + h) * 32 * Sp;

  bf16x8 qf[4];
#pragma unroll
  for (int f = 0; f < 4; ++f)
    qf[f] = *(const bf16x8*)(qbh + (size_t)(q0 + 16 * f + c) * 32 + 8 * g);

  f32x4 oacc[4][2];
#pragma unroll
  for (int f = 0; f < 4; ++f) {
    oacc[f][0] = (f32x4){0.f, 0.f, 0.f, 0.f};
    oacc[f][1] = (f32x4){0.f, 0.f, 0.f, 0.f};
  }
  float ls[4] = {0.f, 0.f, 0.f, 0.f};

  bf16x8 kf[4];
  {
    int k0 = c0 * 64;
#pragma unroll
    for (int t = 0; t < 4; ++t)
      kf[t] = *(const bf16x8*)(kbh + (size_t)(k0 + 16 * t + c) * 32 + 8 * g);
  }

  for (int ch = c0; ch < c1; ++ch) {
    int k0 = ch * 64;
    const f32x4 z = {0.f, 0.f, 0.f, 0.f};
    bool full = (k0 + 64 <= S);
    bf16x8 vf00 = *(const bf16x8*)(vbh + (size_t)c * Sp + k0 + 8 * g);
    bf16x8 vf01 = *(const bf16x8*)(vbh + (size_t)(16 + c) * Sp + k0 + 8 * g);
    bf16x8 vf10 = *(const bf16x8*)(vbh + (size_t)c * Sp + k0 + 32 + 8 * g);
    bf16x8 vf11 = *(const bf16x8*)(vbh + (size_t)(16 + c) * Sp + k0 + 32 + 8 * g);

    // ---- phase kb=0: K-subtiles t=0, t=2 ----
    f32x4 sL[4], sH[4];
    __builtin_amdgcn_s_setprio(1);
#pragma unroll
    for (int f = 0; f < 4; ++f) {
      sL[f] = __builtin_amdgcn_mfma_f32_16x16x32_bf16(kf[0], qf[f], z, 0, 0, 0);
      sH[f] = __builtin_amdgcn_mfma_f32_16x16x32_bf16(kf[2], qf[f], z, 0, 0, 0);
    }
    __builtin_amdgcn_s_setprio(0);
    union { bf16x8 v; unsigned u[4]; } pf[4];
    if (full) {
#pragma unroll
      for (int f = 0; f < 4; ++f) {
        float e0 = __builtin_amdgcn_exp2f(sL[f][0]);
        float e1 = __builtin_amdgcn_exp2f(sL[f][1]);
        float e2 = __builtin_amdgcn_exp2f(sL[f][2]);
        float e3 = __builtin_amdgcn_exp2f(sL[f][3]);
        float e4 = __builtin_amdgcn_exp2f(sH[f][0]);
        float e5 = __builtin_amdgcn_exp2f(sH[f][1]);
        float e6 = __builtin_amdgcn_exp2f(sH[f][2]);
        float e7 = __builtin_amdgcn_exp2f(sH[f][3]);
        ls[f] += ((e0 + e1) + (e2 + e3)) + ((e4 + e5) + (e6 + e7));
        pf[f].u[0] = cvtpk(e0, e1); pf[f].u[1] = cvtpk(e2, e3);
        pf[f].u[2] = cvtpk(e4, e5); pf[f].u[3] = cvtpk(e6, e7);
      }
    } else {
#pragma unroll
      for (int f = 0; f < 4; ++f) {
        float e[8];
#pragma unroll
        for (int r = 0; r < 4; ++r) {
          int keyL = k0 + 8 * g + r;
          int keyH = k0 + 8 * g + 4 + r;
          e[r]     = (keyL < S) ? __builtin_amdgcn_exp2f(sL[f][r]) : 0.f;
          e[4 + r] = (keyH < S) ? __builtin_amdgcn_exp2f(sH[f][r]) : 0.f;
        }
        ls[f] += ((e[0] + e[1]) + (e[2] + e[3])) + ((e[4] + e[5]) + (e[6] + e[7]));
        pf[f].u[0] = cvtpk(e[0], e[1]); pf[f].u[1] = cvtpk(e[2], e[3]);
        pf[f].u[2] = cvtpk(e[4], e[5]); pf[f].u[3] = cvtpk(e[6], e[7]);
      }
    }
    __builtin_amdgcn_s_setprio(1);
#pragma unroll
    for (int f = 0; f < 4; ++f) {
      oacc[f][0] = __builtin_amdgcn_mfma_f32_16x16x32_bf16(vf00, pf[f].v, oacc[f][0], 0, 0, 0);
      oacc[f][1] = __builtin_amdgcn_mfma_f32_16x16x32_bf16(vf01, pf[f].v, oacc[f][1], 0, 0, 0);
    }
    // ---- phase kb=1: K-subtiles t=1, t=3 ----
#pragma unroll
    for (int f = 0; f < 4; ++f) {
      sL[f] = __builtin_amdgcn_mfma_f32_16x16x32_bf16(kf[1], qf[f], z, 0, 0, 0);
      sH[f] = __builtin_amdgcn_mfma_f32_16x16x32_bf16(kf[3], qf[f], z, 0, 0, 0);
    }
    __builtin_amdgcn_s_setprio(0);
    if (ch + 1 < c1) {
      int kn = (ch + 1) * 64;
#pragma unroll
      for (int t = 0; t < 4; ++t)
        kf[t] = *(const bf16x8*)(kbh + (size_t)(kn + 16 * t + c) * 32 + 8 * g);
    }
    if (full) {
#pragma unroll
      for (int f = 0; f < 4; ++f) {
        float e0 = __builtin_amdgcn_exp2f(sL[f][0]);
        float e1 = __builtin_amdgcn_exp2f(sL[f][1]);
        float e2 = __builtin_amdgcn_exp2f(sL[f][2]);
        float e3 = __builtin_amdgcn_exp2f(sL[f][3]);
        float e4 = __builtin_amdgcn_exp2f(sH[f][0]);
        float e5 = __builtin_amdgcn_exp2f(sH[f][1]);
        float e6 = __builtin_amdgcn_exp2f(sH[f][2]);
        float e7 = __builtin_amdgcn_exp2f(sH[f][3]);
        ls[f] += ((e0 + e1) + (e2 + e3)) + ((e4 + e5) + (e6 + e7));
        pf[f].u[0] = cvtpk(e0, e1); pf[f].u[1] = cvtpk(e2, e3);
        pf[f].u[2] = cvtpk(e4, e5); pf[f].u[3] = cvtpk(e6, e7);
      }
    } else {
#pragma unroll
      for (int f = 0; f < 4; ++f) {
        float e[8];
#pragma unroll
        for (int r = 0; r < 4; ++r) {
          int keyL = k0 + 32 + 8 * g + r;
          int keyH = k0 + 32 + 8 * g + 4 + r;
          e[r]     = (keyL < S) ? __builtin_amdgcn_exp2f(sL[f][r]) : 0.f;
          e[4 + r] = (keyH < S) ? __builtin_amdgcn_exp2f(sH[f][r]) : 0.f;
        }
        ls[f] += ((e[0] + e[1]) + (e[2] + e[3])) + ((e[4] + e[5]) + (e[6] + e[7]));
        pf[f].u[0] = cvtpk(e[0], e[1]); pf[f].u[1] = cvtpk(e[2], e[3]);
        pf[f].u[2] = cvtpk(e[4], e[5]); pf[f].u[3] = cvtpk(e[6], e[7]);
      }
    }
    __builtin_amdgcn_s_setprio(1);
#pragma unroll
    for (int f = 0; f < 4; ++f) {
      oacc[f][0] = __builtin_amdgcn_mfma_f32_16x16x32_bf16(vf10, pf[f].v, oacc[f][0], 0, 0, 0);
      oacc[f][1] = __builtin_amdgcn_mfma_f32_16x16x32_bf16(vf11, pf[f].v, oacc[f][1], 0, 0, 0);
    }
    __builtin_amdgcn_s_setprio(0);
  }
#pragma unroll
  for (int f = 0; f < 4; ++f) {
    ls[f] += __shfl_xor(ls[f], 16, 64);
    ls[f] += __shfl_xor(ls[f], 32, 64);
  }
  size_t obase = ((size_t)(ks * 4 + b) * 256 + h * 32) * S;
#pragma unroll
  for (int f = 0; f < 4; ++f) {
    int q = q0 + 16 * f + c;
    if (q < S) {
#pragma unroll
      for (int r = 0; r < 4; ++r) {
        opart[obase + (size_t)(4 * g + r) * S + q]      = f2bf(oacc[f][0][r]);
        opart[obase + (size_t)(16 + 4 * g + r) * S + q] = f2bf(oacc[f][1][r]);
      }
    }
  }
  if (lane < 16) {
    size_t lb = ((size_t)(ks * 4 + b) * 8 + h) * S;
#pragma unroll
    for (int f = 0; f < 4; ++f)
      if (q0 + 16 * f + lane < S) lpart[lb + q0 + 16 * f + lane] = ls[f];
  }
}

__global__ __launch_bounds__(256)
void attn_merged_kernel(const unsigned short* __restrict__ qr_l,
                        const unsigned short* __restrict__ kr_l,
                        const unsigned short* __restrict__ vt_l,
                        unsigned short* __restrict__ op_l, float* __restrict__ lp_l,
                        const unsigned short* __restrict__ qr_g,
                        const unsigned short* __restrict__ kr_g,
                        const unsigned short* __restrict__ vt_g,
                        unsigned short* __restrict__ op_g, float* __restrict__ lp_g) {
  int h = blockIdx.x, b = blockIdx.z, y = blockIdx.y;
  if (y < 27)
    attn_body<3>(qr_l, kr_l, vt_l, op_l, lp_l, 2304, 2304, y / 3, y % 3, h, b, threadIdx.x);
  else
    attn_body<3>(qr_g, kr_g, vt_g, op_g, lp_g, 144, 256, 0, y - 27, h, b, threadIdx.x);
}

// ---------------------------------------------------------------------------
extern "C" void kernel_launch(void* const* d_in, const int* in_sizes, int n_in,
                              void* d_out, int out_size, void* d_ws, size_t ws_size,
                              hipStream_t stream) {
  const float* x        = (const float*)d_in[0];
  const float* w_qkv_l  = (const float*)d_in[1];
  const float* w_proj_l = (const float*)d_in[2];
  const float* b_proj_l = (const float*)d_in[3];
  const float* w_qkv_g  = (const float*)d_in[4];
  const float* w_proj_g = (const float*)d_in[5];
  const float* b_proj_g = (const float*)d_in[6];
  const float* w_f1     = (const float*)d_in[7];
  const float* b_f1     = (const float*)d_in[8];
  const float* w_f2     = (const float*)d_in[9];
  const float* b_f2     = (const float*)d_in[10];
  float* out = (float*)d_out;

  const int S = 2304, Sg = 144, B = 4;
  const int Sp = 2304, Sgp = 256;
  const int KS = 3;

  char* wsp = (char*)d_ws;
  size_t off = 0;
  auto alloc = [&](size_t bytes) { char* p = wsp + off; off = (off + bytes + 255) & ~(size_t)255; return p; };
  unsigned short* opart_l = (unsigned short*)alloc((size_t)KS * B * 256 * S * 2);
  unsigned short* cat = (unsigned short*)alloc((size_t)B * 256 * S * 2);   // bf16, local half
  unsigned short* hbuf = (unsigned short*)alloc((size_t)B * 256 * S * 2);  // bf16
  float* xg    = (float*)alloc((size_t)B * 256 * Sg * 4);
  unsigned short* opart_g = (unsigned short*)alloc((size_t)KS * B * 256 * Sg * 2);
  float* gsm   = (float*)alloc((size_t)B * 256 * Sg * 4);
  unsigned short* qr_l = (unsigned short*)alloc((size_t)B * 8 * Sp * 32 * 2);
  unsigned short* kr_l = (unsigned short*)alloc((size_t)B * 8 * Sp * 32 * 2);
  unsigned short* vt_l = (unsigned short*)alloc((size_t)B * 8 * Sp * 32 * 2);
  unsigned short* qr_g = (unsigned short*)alloc((size_t)B * 8 * Sgp * 32 * 2);
  unsigned short* kr_g = (unsigned short*)alloc((size_t)B * 8 * Sgp * 32 * 2);
  unsigned short* vt_g = (unsigned short*)alloc((size_t)B * 8 * Sgp * 32 * 2);
  unsigned short* whl_qkv_l  = (unsigned short*)alloc((size_t)768 * 256 * 2 * 2);
  unsigned short* whl_proj_l = (unsigned short*)alloc((size_t)256 * 256 * 2 * 2);
  unsigned short* whl_qkv_g  = (unsigned short*)alloc((size_t)768 * 256 * 2 * 2);
  unsigned short* whl_proj_g = (unsigned short*)alloc((size_t)256 * 256 * 2 * 2);
  unsigned short* whl_f1     = (unsigned short*)alloc((size_t)256 * 512 * 2 * 2);
  unsigned short* whl_f2     = (unsigned short*)alloc((size_t)256 * 256 * 2 * 2);
  float* lpart_l = (float*)alloc((size_t)KS * B * 8 * S * 4);
  float* lpart_g = (float*)alloc((size_t)KS * B * 8 * Sg * 4);

  dim3 blk(256);

  // D1: weight split + pool
  prep_kernel<<<dim3(664), blk, 0, stream>>>(
      w_qkv_l, w_proj_l, w_qkv_g, w_proj_g, w_f1, w_f2,
      whl_qkv_l, whl_proj_l, whl_qkv_g, whl_proj_g, whl_f1, whl_f2, x, xg);

  // D2: qkv convs with fused l2norm/convert epilogues (1-term)
  qkv_conv_kernel<<<dim3(36, 12, B), blk, 0, stream>>>(
      whl_qkv_l, x, qr_l, kr_l, vt_l,
      whl_qkv_g, xg, qr_g, kr_g, vt_g);

  // D3: attention (local + global), bf16 opart
  attn_merged_kernel<<<dim3(8, 30, B), blk, 0, stream>>>(
      qr_l, kr_l, vt_l, opart_l, lpart_l, qr_g, kr_g, vt_g, opart_g, lpart_g);

  // D4: proj convs with fused combine (local -> bf16 cat, global -> f32 gsm)
  proj_conv_kernel<<<dim3(36, 8, B), blk, 0, stream>>>(
      whl_proj_l, opart_l, lpart_l, b_proj_l, cat,
      whl_proj_g, opart_g, lpart_g, b_proj_g, gsm);

  // D5: f1 (GELU) with inline bilinear upsample of the global half
  f1_conv_kernel<<<dim3(36, 4, B), blk, 0, stream>>>(
      whl_f1, cat, gsm, b_f1, hbuf);

  // D6: f2
  f2_conv_kernel<<<dim3(36, 4, B), blk, 0, stream>>>(
      whl_f2, hbuf, b_f2, out);
}

// Round 17
// 121.310 us; speedup vs baseline: 1.1460x; 1.1460x over previous
//
#include <hip/hip_runtime.h>
#include <hip/hip_bf16.h>
#include <math.h>

typedef __attribute__((ext_vector_type(8))) short bf16x8;
typedef __attribute__((ext_vector_type(4))) float f32x4;

__device__ inline unsigned short f2bf(float x) {
  __hip_bfloat16 h = __float2bfloat16(x);
  return __builtin_bit_cast(unsigned short, h);
}
__device__ inline float bf2f(unsigned short u) {
  unsigned v = ((unsigned)u) << 16;
  return __builtin_bit_cast(float, v);
}
// One-instruction RNE pack of two f32 -> packed bf16x2 (low = a, high = b).
__device__ inline unsigned cvtpk(float a, float b) {
  unsigned r;
  asm("v_cvt_pk_bf16_f32 %0, %1, %2" : "=v"(r) : "v"(a), "v"(b));
  return r;
}

// ===========================================================================
// D1: weight split (88 blocks) + 4x4 avg pool (576 blocks), fused dispatch.
// ===========================================================================
__global__ __launch_bounds__(256)
void prep_kernel(const float* __restrict__ w0, const float* __restrict__ w1,
                 const float* __restrict__ w2, const float* __restrict__ w3,
                 const float* __restrict__ w4, const float* __restrict__ w5,
                 unsigned short* __restrict__ d0, unsigned short* __restrict__ d1,
                 unsigned short* __restrict__ d2, unsigned short* __restrict__ d3,
                 unsigned short* __restrict__ d4, unsigned short* __restrict__ d5,
                 const float* __restrict__ x, float* __restrict__ xg) {
  int idx = blockIdx.x * 256 + threadIdx.x;
  if (idx < 22528) {
    int r = idx;
    const float* src; unsigned short* dst;
    if (r < 6144) { src = w0; dst = d0; }
    else if (r < 8192) { src = w1; dst = d1; r -= 6144; }
    else if (r < 14336) { src = w2; dst = d2; r -= 8192; }
    else if (r < 16384) { src = w3; dst = d3; r -= 14336; }
    else if (r < 20480) { src = w4; dst = d4; r -= 16384; }
    else { src = w5; dst = d5; r -= 20480; }
    const float* in = src + (size_t)r * 32;
    union { unsigned short u[32]; uint4 q[4]; } H, L;
#pragma unroll
    for (int i = 0; i < 32; ++i) {
      float v = in[i];
      unsigned short h = f2bf(v);
      H.u[i] = h;
      L.u[i] = f2bf(v - bf2f(h));
    }
    uint4* op = (uint4*)(dst + (size_t)r * 64);
#pragma unroll
    for (int q = 0; q < 4; ++q) { op[q] = H.q[q]; op[4 + q] = L.q[q]; }
  } else {
    int p = idx - 22528;
    if (p >= 4 * 256 * 144) return;
    int wc = p % 12;
    int t = p / 12;
    int hc = t % 12;
    int bc = t / 12;
    const float* src = x + ((size_t)bc * 48 + hc * 4) * 48 + wc * 4;
    float s = 0.f;
#pragma unroll
    for (int dy = 0; dy < 4; ++dy)
#pragma unroll
      for (int dx = 0; dx < 4; ++dx) s += src[dy * 48 + dx];
    xg[p] = s * (1.0f / 16.0f);
  }
}

// ===========================================================================
// conv1x1 body: Y = (Whi [+ Wlo]) . Xhi  (+bias, +act). TERMS = 1 or 2.
// CKS>0 : X = bf16 opart partials + f32 lpart denominators (fused combine).
// UPS   : Cin=512; kb<8 reads bf16 X, kb>=8 bilinear-upsamples f32 gsm inline.
// EPI=1 : qkv epilogue — L2-normalize q/k per head and write bf16 q
//         (pre-scaled), permuted k, d-major v directly.
// ===========================================================================
template<int ACT, int OT, int CKS, int UPS, int EPI, int TERMS, typename XT, typename YT>
__device__ __forceinline__
void conv_body(const unsigned short* __restrict__ Whl, const XT* __restrict__ X,
               const float* __restrict__ lpart, const float* __restrict__ bias,
               YT* __restrict__ Y, const float* __restrict__ gsm,
               unsigned short* __restrict__ qd, unsigned short* __restrict__ kd,
               unsigned short* __restrict__ vt, int Sp,
               int Cin, int S, size_t XbS, size_t YbS,
               int bx, int by, int bz, int tid) {
  constexpr int OI = OT / 64;
  __shared__ __align__(16) unsigned short Bs[64 * 32];  // 4 KB
  const int w = tid >> 6, lane = tid & 63;
  const int g = lane >> 4, c = lane & 15;
  const int s0 = bx * 64;
  const int o0 = by * OT;
  const int b = bz;
  const int KB = Cin >> 5;
  const int sRow = tid & 63;
  const int jS = tid >> 6;
  const int ss = s0 + sRow;
  const bool sIn = (ss < S);
  unsigned short* BsRow = Bs + sRow * 32;
  const int hiOff = (jS ^ ((sRow >> 1) & 3)) * 8;

  int t00 = 0, t01 = 0, t10 = 0, t11 = 0;
  float w00 = 0.f, w01 = 0.f, w10 = 0.f, w11 = 0.f;
  if constexpr (UPS) {
    if (sIn) {
      int yo = ss / 48, xo = ss % 48;
      float sy = 0.25f * yo - 0.375f;
      float sx = 0.25f * xo - 0.375f;
      int y0 = (int)floorf(sy); float fy = sy - (float)y0;
      int x0 = (int)floorf(sx); float fx = sx - (float)x0;
      int y0c = min(11, max(0, y0)), y1c = min(11, max(0, y0 + 1));
      int x0c = min(11, max(0, x0)), x1c = min(11, max(0, x0 + 1));
      t00 = y0c * 12 + x0c; t01 = y0c * 12 + x1c;
      t10 = y1c * 12 + x0c; t11 = y1c * 12 + x1c;
      w00 = (1.f - fy) * (1.f - fx); w01 = (1.f - fy) * fx;
      w10 = fy * (1.f - fx);         w11 = fy * fx;
    }
  }

  f32x4 acc[OI][4];
#pragma unroll
  for (int oi = 0; oi < OI; ++oi)
#pragma unroll
    for (int si = 0; si < 4; ++si) acc[oi][si] = (f32x4){0.f, 0.f, 0.f, 0.f};

  for (int kb = 0; kb < KB; ++kb) {
    union { unsigned u[4]; bf16x8 v; } hu;
    if (sIn) {
      if constexpr (CKS > 0) {
        // fused attention-combine: head index == kb; opart is bf16.
        const unsigned short* xp = (const unsigned short*)X + (size_t)b * XbS +
                                   (size_t)(kb * 32 + 8 * jS) * S + ss;
        const float* lp = lpart + ((size_t)b * 8 + kb) * S + ss;
        float den = 0.f;
        float num[8] = {0.f, 0.f, 0.f, 0.f, 0.f, 0.f, 0.f, 0.f};
#pragma unroll
        for (int ksi = 0; ksi < CKS; ++ksi) {
          den += lp[(size_t)ksi * 32 * S];
#pragma unroll
          for (int i = 0; i < 8; ++i)
            num[i] += bf2f(xp[(size_t)(ksi * 1024 + i) * S]);
        }
        float rd = 1.0f / den;
#pragma unroll
        for (int i = 0; i < 4; ++i)
          hu.u[i] = cvtpk(num[2 * i] * rd, num[2 * i + 1] * rd);
      } else if constexpr (UPS) {
        if (kb < 8) {
          const XT* xp = X + (size_t)b * XbS + (size_t)(kb * 32 + 8 * jS) * S + ss;
#pragma unroll
          for (int i = 0; i < 4; ++i) {
            unsigned lo = *(const unsigned short*)(xp + (size_t)(2 * i) * S);
            unsigned hi = *(const unsigned short*)(xp + (size_t)(2 * i + 1) * S);
            hu.u[i] = lo | (hi << 16);
          }
        } else {
          const float* gbb = gsm + (size_t)b * 256 * 144 +
                             (size_t)((kb - 8) * 32 + 8 * jS) * 144;
#pragma unroll
          for (int i = 0; i < 4; ++i) {
            const float* g0 = gbb + (size_t)(2 * i) * 144;
            const float* g1 = gbb + (size_t)(2 * i + 1) * 144;
            float v0 = w00 * g0[t00] + w01 * g0[t01] + w10 * g0[t10] + w11 * g0[t11];
            float v1 = w00 * g1[t00] + w01 * g1[t01] + w10 * g1[t10] + w11 * g1[t11];
            hu.u[i] = cvtpk(v0, v1);
          }
        }
      } else if constexpr (sizeof(XT) == 2) {
        const XT* xp = X + (size_t)b * XbS + (size_t)(kb * 32 + 8 * jS) * S + ss;
#pragma unroll
        for (int i = 0; i < 4; ++i) {
          unsigned lo = *(const unsigned short*)(xp + (size_t)(2 * i) * S);
          unsigned hi = *(const unsigned short*)(xp + (size_t)(2 * i + 1) * S);
          hu.u[i] = lo | (hi << 16);
        }
      } else {
        const float* xp = (const float*)X + (size_t)b * XbS +
                          (size_t)(kb * 32 + 8 * jS) * S + ss;
#pragma unroll
        for (int i = 0; i < 4; ++i)
          hu.u[i] = cvtpk(xp[(size_t)(2 * i) * S], xp[(size_t)(2 * i + 1) * S]);
      }
    } else {
#pragma unroll
      for (int i = 0; i < 4; ++i) hu.u[i] = 0;
    }
    bf16x8 ahi[OI], alo[OI];
#pragma unroll
    for (int oi = 0; oi < OI; ++oi) {
      const unsigned short* ap =
          Whl + ((size_t)(o0 + 16 * OI * w + 16 * oi + c) * KB + kb) * 64;
      ahi[oi] = *(const bf16x8*)(ap + 8 * g);
      if constexpr (TERMS == 2) alo[oi] = *(const bf16x8*)(ap + 32 + 8 * g);
    }
    __syncthreads();
    *(bf16x8*)(BsRow + hiOff) = hu.v;
    __syncthreads();
    bf16x8 bhi[4];
#pragma unroll
    for (int si = 0; si < 4; ++si) {
      int row = 16 * si + c;
      const unsigned short* bp = Bs + row * 32;
      bhi[si] = *(const bf16x8*)(bp + ((g ^ ((row >> 1) & 3)) * 8));
    }
#pragma unroll
    for (int oi = 0; oi < OI; ++oi)
#pragma unroll
      for (int si = 0; si < 4; ++si) {
        acc[oi][si] = __builtin_amdgcn_mfma_f32_16x16x32_bf16(ahi[oi], bhi[si], acc[oi][si], 0, 0, 0);
        if constexpr (TERMS == 2)
          acc[oi][si] = __builtin_amdgcn_mfma_f32_16x16x32_bf16(alo[oi], bhi[si], acc[oi][si], 0, 0, 0);
      }
  }

  if constexpr (EPI == 1) {
    // qkv fused epilogue. o = o0 + 32w + 16oi + 4g + r; sec: 0=q 1=k 2=v.
    int sec = o0 >> 8;
    int h = ((o0 >> 5) & 7) + w;
    if (sec == 2) {
      unsigned short* vb = vt + (size_t)(b * 8 + h) * 32 * Sp;
#pragma unroll
      for (int oi = 0; oi < OI; ++oi)
#pragma unroll
        for (int r = 0; r < 4; ++r) {
          int d = 16 * oi + 4 * g + r;
#pragma unroll
          for (int si = 0; si < 4; ++si) {
            int s = s0 + 16 * si + c;
            if (s < S) vb[(size_t)d * Sp + s] = f2bf(acc[oi][si][r]);
          }
        }
    } else {
      float invs[4];
#pragma unroll
      for (int si = 0; si < 4; ++si) {
        float t = 0.f;
#pragma unroll
        for (int oi = 0; oi < OI; ++oi)
#pragma unroll
          for (int r = 0; r < 4; ++r) t += acc[oi][si][r] * acc[oi][si][r];
        t += __shfl_xor(t, 16, 64);
        t += __shfl_xor(t, 32, 64);
        float inv = 1.0f / fmaxf(sqrtf(t), 1e-12f);
        if (sec == 0) inv *= 0.25506607138105343f;  // 32^-0.5 * log2(e)
        invs[si] = inv;
      }
      unsigned short* dstp = (sec == 0) ? qd : kd;
#pragma unroll
      for (int si = 0; si < 4; ++si) {
        int s = s0 + 16 * si + c;
        if (s >= S) continue;
        int srow = s;
        if (sec == 1) {
          int blk2 = s >> 6, j = s & 63;
          srow = (blk2 << 6) + 32 * ((j >> 2) & 1) + 16 * (j >> 5) + 4 * ((j >> 3) & 3) + (j & 3);
        }
        unsigned short* rowp = dstp + ((size_t)(b * 8 + h) * Sp + srow) * 32;
#pragma unroll
        for (int oi = 0; oi < OI; ++oi) {
          int d0 = 16 * oi + 4 * g;
          *(unsigned*)(rowp + d0)     = cvtpk(acc[oi][si][0] * invs[si], acc[oi][si][1] * invs[si]);
          *(unsigned*)(rowp + d0 + 2) = cvtpk(acc[oi][si][2] * invs[si], acc[oi][si][3] * invs[si]);
        }
      }
    }
    return;
  }

#pragma unroll
  for (int oi = 0; oi < OI; ++oi) {
#pragma unroll
    for (int r = 0; r < 4; ++r) {
      int o = o0 + 16 * OI * w + 16 * oi + 4 * g + r;
      float bv = bias ? bias[o] : 0.f;
#pragma unroll
      for (int si = 0; si < 4; ++si) {
        int s = s0 + 16 * si + c;
        if (s < S) {
          float v = acc[oi][si][r] + bv;
          if (ACT == 1) v = v * 0.5f * (1.0f + erff(v * 0.70710678118654752f));
          if constexpr (sizeof(YT) == 2)
            Y[(size_t)b * YbS + (size_t)o * S + s] = (YT)f2bf(v);
          else
            Y[(size_t)b * YbS + (size_t)o * S + s] = v;
        }
      }
    }
  }
}

// D2: qkv convs (1-term) with fused l2norm/convert epilogue.
__global__ __launch_bounds__(256)
void qkv_conv_kernel(const unsigned short* __restrict__ Wl, const float* __restrict__ Xl,
                     unsigned short* __restrict__ qr_l, unsigned short* __restrict__ kr_l,
                     unsigned short* __restrict__ vt_l,
                     const unsigned short* __restrict__ Wg, const float* __restrict__ Xg,
                     unsigned short* __restrict__ qr_g, unsigned short* __restrict__ kr_g,
                     unsigned short* __restrict__ vt_g) {
  if (blockIdx.y < 6) {
    conv_body<0, 128, 0, 0, 1, 1, float, float>(Wl, Xl, nullptr, nullptr, (float*)nullptr, nullptr,
        qr_l, kr_l, vt_l, 2304,
        256, 2304, (size_t)256 * 2304, 0,
        blockIdx.x, blockIdx.y, blockIdx.z, threadIdx.x);
  } else {
    if (blockIdx.x >= 3) return;
    conv_body<0, 128, 0, 0, 1, 1, float, float>(Wg, Xg, nullptr, nullptr, (float*)nullptr, nullptr,
        qr_g, kr_g, vt_g, 256,
        256, 144, (size_t)256 * 144, 0,
        blockIdx.x, blockIdx.y - 6, blockIdx.z, threadIdx.x);
  }
}

// D4: proj convs with fused attention-combine (bf16 opart).
__global__ __launch_bounds__(256)
void proj_conv_kernel(const unsigned short* __restrict__ Wl, const unsigned short* __restrict__ opl,
                      const float* __restrict__ lpl, const float* __restrict__ bl,
                      unsigned short* __restrict__ cat,
                      const unsigned short* __restrict__ Wg, const unsigned short* __restrict__ opg,
                      const float* __restrict__ lpg, const float* __restrict__ bg,
                      float* __restrict__ gsm) {
  if (blockIdx.y < 4) {
    conv_body<0, 64, 3, 0, 0, 2, unsigned short, unsigned short>(Wl, opl, lpl, bl, cat, nullptr,
        nullptr, nullptr, nullptr, 0,
        256, 2304, (size_t)256 * 2304, (size_t)256 * 2304,
        blockIdx.x, blockIdx.y, blockIdx.z, threadIdx.x);
  } else {
    if (blockIdx.x >= 3) return;
    conv_body<0, 64, 3, 0, 0, 2, unsigned short, float>(Wg, opg, lpg, bg, gsm, nullptr,
        nullptr, nullptr, nullptr, 0,
        256, 144, (size_t)256 * 144, (size_t)256 * 144,
        blockIdx.x, blockIdx.y - 4, blockIdx.z, threadIdx.x);
  }
}

// D5: f1 conv (GELU) with inline bilinear upsample for channels 256..511.
__global__ __launch_bounds__(256)
void f1_conv_kernel(const unsigned short* __restrict__ W, const unsigned short* __restrict__ cat,
                    const float* __restrict__ gsm, const float* __restrict__ bias,
                    unsigned short* __restrict__ hbuf) {
  conv_body<1, 64, 0, 1, 0, 2, unsigned short, unsigned short>(W, cat, nullptr, bias, hbuf, gsm,
      nullptr, nullptr, nullptr, 0,
      512, 2304, (size_t)256 * 2304, (size_t)256 * 2304,
      blockIdx.x, blockIdx.y, blockIdx.z, threadIdx.x);
}

// D6: f2 conv, bf16 in -> f32 out.
__global__ __launch_bounds__(256)
void f2_conv_kernel(const unsigned short* __restrict__ W, const unsigned short* __restrict__ hbuf,
                    const float* __restrict__ bias, float* __restrict__ out) {
  conv_body<0, 64, 0, 0, 0, 2, unsigned short, float>(W, hbuf, nullptr, bias, out, nullptr,
      nullptr, nullptr, nullptr, 0,
      256, 2304, (size_t)256 * 2304, (size_t)256 * 2304,
      blockIdx.x, blockIdx.y, blockIdx.z, threadIdx.x);
}

// ===========================================================================
// D3: MFMA flash attention (round-15 body; bf16 opart).
// 64 q-rows/wave, K-split KS=3, phase-paired softmax, K prefetch 1 ahead.
// GRID (8=h, 27 local + 3 global, b): lin%8==h pins heads to XCDs.
// ===========================================================================
template<int KS>
__device__ __forceinline__
void attn_body(const unsigned short* __restrict__ qr, const unsigned short* __restrict__ kr,
               const unsigned short* __restrict__ vt, unsigned short* __restrict__ opart,
               float* __restrict__ lpart, int S, int Sp, int qblk, int ks,
               int h, int b, int tidx) {
  int w = tidx >> 6, lane = tidx & 63;
  int g = lane >> 4, c = lane & 15;
  int q0 = qblk * 256 + w * 64;
  const int chunks = Sp >> 6;
  const int c0 = (ks * chunks) / KS, c1 = ((ks + 1) * chunks) / KS;
  const unsigned short* qbh = qr + (size_t)(b * 8 + h) * Sp * 32;
  const unsigned short* kbh = kr + (size_t)(b * 8 + h) * Sp * 32;
  const unsigned short* vbh = vt + (size_t)(b * 8 + h) * 32 * Sp;

  bf16x8 qf[4];
#pragma unroll
  for (int f = 0; f < 4; ++f)
    qf[f] = *(const bf16x8*)(qbh + (size_t)(q0 + 16 * f + c) * 32 + 8 * g);

  f32x4 oacc[4][2];
#pragma unroll
  for (int f = 0; f < 4; ++f) {
    oacc[f][0] = (f32x4){0.f, 0.f, 0.f, 0.f};
    oacc[f][1] = (f32x4){0.f, 0.f, 0.f, 0.f};
  }
  float ls[4] = {0.f, 0.f, 0.f, 0.f};

  bf16x8 kf[4];
  {
    int k0 = c0 * 64;
#pragma unroll
    for (int t = 0; t < 4; ++t)
      kf[t] = *(const bf16x8*)(kbh + (size_t)(k0 + 16 * t + c) * 32 + 8 * g);
  }

  for (int ch = c0; ch < c1; ++ch) {
    int k0 = ch * 64;
    const f32x4 z = {0.f, 0.f, 0.f, 0.f};
    bool full = (k0 + 64 <= S);
    bf16x8 vf00 = *(const bf16x8*)(vbh + (size_t)c * Sp + k0 + 8 * g);
    bf16x8 vf01 = *(const bf16x8*)(vbh + (size_t)(16 + c) * Sp + k0 + 8 * g);
    bf16x8 vf10 = *(const bf16x8*)(vbh + (size_t)c * Sp + k0 + 32 + 8 * g);
    bf16x8 vf11 = *(const bf16x8*)(vbh + (size_t)(16 + c) * Sp + k0 + 32 + 8 * g);

    // ---- phase kb=0: K-subtiles t=0, t=2 ----
    f32x4 sL[4], sH[4];
    __builtin_amdgcn_s_setprio(1);
#pragma unroll
    for (int f = 0; f < 4; ++f) {
      sL[f] = __builtin_amdgcn_mfma_f32_16x16x32_bf16(kf[0], qf[f], z, 0, 0, 0);
      sH[f] = __builtin_amdgcn_mfma_f32_16x16x32_bf16(kf[2], qf[f], z, 0, 0, 0);
    }
    __builtin_amdgcn_s_setprio(0);
    union { bf16x8 v; unsigned u[4]; } pf[4];
    if (full) {
#pragma unroll
      for (int f = 0; f < 4; ++f) {
        float e0 = __builtin_amdgcn_exp2f(sL[f][0]);
        float e1 = __builtin_amdgcn_exp2f(sL[f][1]);
        float e2 = __builtin_amdgcn_exp2f(sL[f][2]);
        float e3 = __builtin_amdgcn_exp2f(sL[f][3]);
        float e4 = __builtin_amdgcn_exp2f(sH[f][0]);
        float e5 = __builtin_amdgcn_exp2f(sH[f][1]);
        float e6 = __builtin_amdgcn_exp2f(sH[f][2]);
        float e7 = __builtin_amdgcn_exp2f(sH[f][3]);
        ls[f] += ((e0 + e1) + (e2 + e3)) + ((e4 + e5) + (e6 + e7));
        pf[f].u[0] = cvtpk(e0, e1); pf[f].u[1] = cvtpk(e2, e3);
        pf[f].u[2] = cvtpk(e4, e5); pf[f].u[3] = cvtpk(e6, e7);
      }
    } else {
#pragma unroll
      for (int f = 0; f < 4; ++f) {
        float e[8];
#pragma unroll
        for (int r = 0; r < 4; ++r) {
          int keyL = k0 + 8 * g + r;
          int keyH = k0 + 8 * g + 4 + r;
          e[r]     = (keyL < S) ? __builtin_amdgcn_exp2f(sL[f][r]) : 0.f;
          e[4 + r] = (keyH < S) ? __builtin_amdgcn_exp2f(sH[f][r]) : 0.f;
        }
        ls[f] += ((e[0] + e[1]) + (e[2] + e[3])) + ((e[4] + e[5]) + (e[6] + e[7]));
        pf[f].u[0] = cvtpk(e[0], e[1]); pf[f].u[1] = cvtpk(e[2], e[3]);
        pf[f].u[2] = cvtpk(e[4], e[5]); pf[f].u[3] = cvtpk(e[6], e[7]);
      }
    }
    __builtin_amdgcn_s_setprio(1);
#pragma unroll
    for (int f = 0; f < 4; ++f) {
      oacc[f][0] = __builtin_amdgcn_mfma_f32_16x16x32_bf16(vf00, pf[f].v, oacc[f][0], 0, 0, 0);
      oacc[f][1] = __builtin_amdgcn_mfma_f32_16x16x32_bf16(vf01, pf[f].v, oacc[f][1], 0, 0, 0);
    }
    // ---- phase kb=1: K-subtiles t=1, t=3 ----
#pragma unroll
    for (int f = 0; f < 4; ++f) {
      sL[f] = __builtin_amdgcn_mfma_f32_16x16x32_bf16(kf[1], qf[f], z, 0, 0, 0);
      sH[f] = __builtin_amdgcn_mfma_f32_16x16x32_bf16(kf[3], qf[f], z, 0, 0, 0);
    }
    __builtin_amdgcn_s_setprio(0);
    if (ch + 1 < c1) {
      int kn = (ch + 1) * 64;
#pragma unroll
      for (int t = 0; t < 4; ++t)
        kf[t] = *(const bf16x8*)(kbh + (size_t)(kn + 16 * t + c) * 32 + 8 * g);
    }
    if (full) {
#pragma unroll
      for (int f = 0; f < 4; ++f) {
        float e0 = __builtin_amdgcn_exp2f(sL[f][0]);
        float e1 = __builtin_amdgcn_exp2f(sL[f][1]);
        float e2 = __builtin_amdgcn_exp2f(sL[f][2]);
        float e3 = __builtin_amdgcn_exp2f(sL[f][3]);
        float e4 = __builtin_amdgcn_exp2f(sH[f][0]);
        float e5 = __builtin_amdgcn_exp2f(sH[f][1]);
        float e6 = __builtin_amdgcn_exp2f(sH[f][2]);
        float e7 = __builtin_amdgcn_exp2f(sH[f][3]);
        ls[f] += ((e0 + e1) + (e2 + e3)) + ((e4 + e5) + (e6 + e7));
        pf[f].u[0] = cvtpk(e0, e1); pf[f].u[1] = cvtpk(e2, e3);
        pf[f].u[2] = cvtpk(e4, e5); pf[f].u[3] = cvtpk(e6, e7);
      }
    } else {
#pragma unroll
      for (int f = 0; f < 4; ++f) {
        float e[8];
#pragma unroll
        for (int r = 0; r < 4; ++r) {
          int keyL = k0 + 32 + 8 * g + r;
          int keyH = k0 + 32 + 8 * g + 4 + r;
          e[r]     = (keyL < S) ? __builtin_amdgcn_exp2f(sL[f][r]) : 0.f;
          e[4 + r] = (keyH < S) ? __builtin_amdgcn_exp2f(sH[f][r]) : 0.f;
        }
        ls[f] += ((e[0] + e[1]) + (e[2] + e[3])) + ((e[4] + e[5]) + (e[6] + e[7]));
        pf[f].u[0] = cvtpk(e[0], e[1]); pf[f].u[1] = cvtpk(e[2], e[3]);
        pf[f].u[2] = cvtpk(e[4], e[5]); pf[f].u[3] = cvtpk(e[6], e[7]);
      }
    }
    __builtin_amdgcn_s_setprio(1);
#pragma unroll
    for (int f = 0; f < 4; ++f) {
      oacc[f][0] = __builtin_amdgcn_mfma_f32_16x16x32_bf16(vf10, pf[f].v, oacc[f][0], 0, 0, 0);
      oacc[f][1] = __builtin_amdgcn_mfma_f32_16x16x32_bf16(vf11, pf[f].v, oacc[f][1], 0, 0, 0);
    }
    __builtin_amdgcn_s_setprio(0);
  }
#pragma unroll
  for (int f = 0; f < 4; ++f) {
    ls[f] += __shfl_xor(ls[f], 16, 64);
    ls[f] += __shfl_xor(ls[f], 32, 64);
  }
  size_t obase = ((size_t)(ks * 4 + b) * 256 + h * 32) * S;
#pragma unroll
  for (int f = 0; f < 4; ++f) {
    int q = q0 + 16 * f + c;
    if (q < S) {
#pragma unroll
      for (int r = 0; r < 4; ++r) {
        opart[obase + (size_t)(4 * g + r) * S + q]      = f2bf(oacc[f][0][r]);
        opart[obase + (size_t)(16 + 4 * g + r) * S + q] = f2bf(oacc[f][1][r]);
      }
    }
  }
  if (lane < 16) {
    size_t lb = ((size_t)(ks * 4 + b) * 8 + h) * S;
#pragma unroll
    for (int f = 0; f < 4; ++f)
      if (q0 + 16 * f + lane < S) lpart[lb + q0 + 16 * f + lane] = ls[f];
  }
}

__global__ __launch_bounds__(256)
void attn_merged_kernel(const unsigned short* __restrict__ qr_l,
                        const unsigned short* __restrict__ kr_l,
                        const unsigned short* __restrict__ vt_l,
                        unsigned short* __restrict__ op_l, float* __restrict__ lp_l,
                        const unsigned short* __restrict__ qr_g,
                        const unsigned short* __restrict__ kr_g,
                        const unsigned short* __restrict__ vt_g,
                        unsigned short* __restrict__ op_g, float* __restrict__ lp_g) {
  int h = blockIdx.x, b = blockIdx.z, y = blockIdx.y;
  if (y < 27)
    attn_body<3>(qr_l, kr_l, vt_l, op_l, lp_l, 2304, 2304, y / 3, y % 3, h, b, threadIdx.x);
  else
    attn_body<3>(qr_g, kr_g, vt_g, op_g, lp_g, 144, 256, 0, y - 27, h, b, threadIdx.x);
}

// ---------------------------------------------------------------------------
extern "C" void kernel_launch(void* const* d_in, const int* in_sizes, int n_in,
                              void* d_out, int out_size, void* d_ws, size_t ws_size,
                              hipStream_t stream) {
  const float* x        = (const float*)d_in[0];
  const float* w_qkv_l  = (const float*)d_in[1];
  const float* w_proj_l = (const float*)d_in[2];
  const float* b_proj_l = (const float*)d_in[3];
  const float* w_qkv_g  = (const float*)d_in[4];
  const float* w_proj_g = (const float*)d_in[5];
  const float* b_proj_g = (const float*)d_in[6];
  const float* w_f1     = (const float*)d_in[7];
  const float* b_f1     = (const float*)d_in[8];
  const float* w_f2     = (const float*)d_in[9];
  const float* b_f2     = (const float*)d_in[10];
  float* out = (float*)d_out;

  const int S = 2304, Sg = 144, B = 4;
  const int Sp = 2304, Sgp = 256;
  const int KS = 3;

  char* wsp = (char*)d_ws;
  size_t off = 0;
  auto alloc = [&](size_t bytes) { char* p = wsp + off; off = (off + bytes + 255) & ~(size_t)255; return p; };
  unsigned short* opart_l = (unsigned short*)alloc((size_t)KS * B * 256 * S * 2);
  unsigned short* cat = (unsigned short*)alloc((size_t)B * 256 * S * 2);   // bf16, local half
  unsigned short* hbuf = (unsigned short*)alloc((size_t)B * 256 * S * 2);  // bf16
  float* xg    = (float*)alloc((size_t)B * 256 * Sg * 4);
  unsigned short* opart_g = (unsigned short*)alloc((size_t)KS * B * 256 * Sg * 2);
  float* gsm   = (float*)alloc((size_t)B * 256 * Sg * 4);
  unsigned short* qr_l = (unsigned short*)alloc((size_t)B * 8 * Sp * 32 * 2);
  unsigned short* kr_l = (unsigned short*)alloc((size_t)B * 8 * Sp * 32 * 2);
  unsigned short* vt_l = (unsigned short*)alloc((size_t)B * 8 * Sp * 32 * 2);
  unsigned short* qr_g = (unsigned short*)alloc((size_t)B * 8 * Sgp * 32 * 2);
  unsigned short* kr_g = (unsigned short*)alloc((size_t)B * 8 * Sgp * 32 * 2);
  unsigned short* vt_g = (unsigned short*)alloc((size_t)B * 8 * Sgp * 32 * 2);
  unsigned short* whl_qkv_l  = (unsigned short*)alloc((size_t)768 * 256 * 2 * 2);
  unsigned short* whl_proj_l = (unsigned short*)alloc((size_t)256 * 256 * 2 * 2);
  unsigned short* whl_qkv_g  = (unsigned short*)alloc((size_t)768 * 256 * 2 * 2);
  unsigned short* whl_proj_g = (unsigned short*)alloc((size_t)256 * 256 * 2 * 2);
  unsigned short* whl_f1     = (unsigned short*)alloc((size_t)256 * 512 * 2 * 2);
  unsigned short* whl_f2     = (unsigned short*)alloc((size_t)256 * 256 * 2 * 2);
  float* lpart_l = (float*)alloc((size_t)KS * B * 8 * S * 4);
  float* lpart_g = (float*)alloc((size_t)KS * B * 8 * Sg * 4);

  dim3 blk(256);

  // D1: weight split + pool
  prep_kernel<<<dim3(664), blk, 0, stream>>>(
      w_qkv_l, w_proj_l, w_qkv_g, w_proj_g, w_f1, w_f2,
      whl_qkv_l, whl_proj_l, whl_qkv_g, whl_proj_g, whl_f1, whl_f2, x, xg);

  // D2: qkv convs with fused l2norm/convert epilogues (1-term)
  qkv_conv_kernel<<<dim3(36, 12, B), blk, 0, stream>>>(
      whl_qkv_l, x, qr_l, kr_l, vt_l,
      whl_qkv_g, xg, qr_g, kr_g, vt_g);

  // D3: attention (local + global), bf16 opart
  attn_merged_kernel<<<dim3(8, 30, B), blk, 0, stream>>>(
      qr_l, kr_l, vt_l, opart_l, lpart_l, qr_g, kr_g, vt_g, opart_g, lpart_g);

  // D4: proj convs with fused combine (local -> bf16 cat, global -> f32 gsm)
  proj_conv_kernel<<<dim3(36, 8, B), blk, 0, stream>>>(
      whl_proj_l, opart_l, lpart_l, b_proj_l, cat,
      whl_proj_g, opart_g, lpart_g, b_proj_g, gsm);

  // D5: f1 (GELU) with inline bilinear upsample of the global half
  f1_conv_kernel<<<dim3(36, 4, B), blk, 0, stream>>>(
      whl_f1, cat, gsm, b_f1, hbuf);

  // D6: f2
  f2_conv_kernel<<<dim3(36, 4, B), blk, 0, stream>>>(
      whl_f2, hbuf, b_f2, out);
}